// Round 4
// baseline (49.071 us; speedup 1.0000x reference)
//
#include <hip/hip_runtime.h>

#define NBATCH 32
#define LPATH 256
#define NSEG 255
#define SIGLEN 4680       // 8 + 64 + 512 + 4096
#define INV6 (1.0f/6.0f)
#define INV24 (1.0f/24.0f)

// Per-signature LDS buffer, exchange-friendly layouts:
//  T4t : level-4 transposed [ (c*8+e)*64 + (a*8+b) ]
//  T3b : level-3 padded      [ x*68 + y*8 + z ]
//  T2  : [ a*8+b ]    T1 : [ a ]
struct __align__(16) CBuf {
    float T4t[64 * 64];   // 16384 B
    float T3b[8 * 68];    //  2176 B
    float T2[64];         //   256 B
    float T1[8];          //    32 B
};                        // 18848 B; x8 = 150784 B LDS

__device__ __forceinline__ void publish_sig(CBuf& B, const float S4[64],
                                            const float S3[8], float S2, float a1a,
                                            int l, int a, int b) {
    #pragma unroll
    for (int c = 0; c < 8; ++c)
        #pragma unroll
        for (int e = 0; e < 8; ++e)
            B.T4t[(c * 8 + e) * 64 + l] = S4[c * 8 + e];
    #pragma unroll
    for (int c = 0; c < 8; ++c)
        B.T3b[a * 68 + b * 8 + c] = S3[c];
    B.T2[l] = S2;
    if (b == 0) B.T1[a] = a1a;
}

__device__ __forceinline__ void absorb_sig(const CBuf& B, float S4[64], float S3[8],
                                           float& S2, float& a1a, int l, int a, int b) {
    const float4 t1lo = *(const float4*)&B.T1[0];
    const float4 t1hi = *(const float4*)&B.T1[4];
    const float t1r[8] = {t1lo.x, t1lo.y, t1lo.z, t1lo.w,
                          t1hi.x, t1hi.y, t1hi.z, t1hi.w};
    const float t1a = B.T1[a];
    const float t1b = B.T1[b];
    #pragma unroll
    for (int c = 0; c < 8; ++c) {
        const float4 t2lo = *(const float4*)&B.T2[c * 8];
        const float4 t2hi = *(const float4*)&B.T2[c * 8 + 4];
        const float t2r[8] = {t2lo.x, t2lo.y, t2lo.z, t2lo.w,
                              t2hi.x, t2hi.y, t2hi.z, t2hi.w};
        const float4 t3lo = *(const float4*)&B.T3b[b * 68 + c * 8];
        const float4 t3hi = *(const float4*)&B.T3b[b * 68 + c * 8 + 4];
        const float t3r[8] = {t3lo.x, t3lo.y, t3lo.z, t3lo.w,
                              t3hi.x, t3hi.y, t3hi.z, t3hi.w};
        #pragma unroll
        for (int e = 0; e < 8; ++e)
            S4[c * 8 + e] += S3[c] * t1r[e] + S2 * t2r[e]
                           + a1a * t3r[e] + B.T4t[(c * 8 + e) * 64 + l];
    }
    #pragma unroll
    for (int c = 0; c < 8; ++c)
        S3[c] += S2 * t1r[c] + a1a * B.T2[b * 8 + c] + B.T3b[a * 68 + b * 8 + c];
    S2 += a1a * t1b + B.T2[l];
    a1a += t1a;
}

// One block per batch; 1024 threads = 16 waves. Wave w scans segments
// [16w,16w+16) (seg 255 padded to identity), then: round0 wave-pair combine,
// survivors publish to 8 CBufs, rounds 1-3 all-thread parallel Chen products.
__global__ __launch_bounds__(1024, 4) void sig_kernel(const float* __restrict__ path,
                                                      float* __restrict__ out) {
    const int n = blockIdx.x;
    const int t = threadIdx.x;
    const int w = t >> 6, l = t & 63, a = l >> 3, b = l & 7;

    __shared__ CBuf bufs[8];

    const float* prow = path + n * (LPATH * 8);

    float S4[64], S3[8], S2 = 0.f, a1a = 0.f;
    #pragma unroll
    for (int j = 0; j < 64; ++j) S4[j] = 0.f;
    #pragma unroll
    for (int c = 0; c < 8; ++c) S3[c] = 0.f;

    // ---- scan 16 segments, fully unrolled; d straight from global (L1/L2-hot) ----
    #pragma unroll
    for (int ss = 0; ss < 16; ++ss) {
        const int s = w * 16 + ss;
        const int s1 = (s < NSEG) ? s + 1 : s;   // pad: d = 0 == identity
        const float4 alo = *(const float4*)&prow[s * 8];
        const float4 ahi = *(const float4*)&prow[s * 8 + 4];
        const float4 blo = *(const float4*)&prow[s1 * 8];
        const float4 bhi = *(const float4*)&prow[s1 * 8 + 4];
        const float dr[8] = {blo.x - alo.x, blo.y - alo.y, blo.z - alo.z, blo.w - alo.w,
                             bhi.x - ahi.x, bhi.y - ahi.y, bhi.z - ahi.z, bhi.w - ahi.w};
        const float da = prow[s1 * 8 + a] - prow[s * 8 + a];
        const float db = prow[s1 * 8 + b] - prow[s * 8 + b];
        const float dab = da * db;
        const float P = dab * INV24 + a1a * db * INV6 + S2 * 0.5f;
        const float Q = dab * INV6  + a1a * db * 0.5f + S2;
        float K[8];
        #pragma unroll
        for (int c = 0; c < 8; ++c) K[c] = dr[c] * P + S3[c];
        #pragma unroll
        for (int c = 0; c < 8; ++c)
            #pragma unroll
            for (int e = 0; e < 8; ++e)
                S4[c * 8 + e] += dr[e] * K[c];
        #pragma unroll
        for (int c = 0; c < 8; ++c) S3[c] += dr[c] * Q;
        S2 += db * (da * 0.5f + a1a);
        a1a += da;
    }

    // ---- round 0: wave-pair tree (odd waves publish, even absorb) ----
    if (w & 1) publish_sig(bufs[w >> 1], S4, S3, S2, a1a, l, a, b);
    __syncthreads();
    if (!(w & 1)) absorb_sig(bufs[w >> 1], S4, S3, S2, a1a, l, a, b);
    __syncthreads();

    // ---- survivors (even waves) publish combined sigs into bufs[0..7] ----
    if (!(w & 1)) publish_sig(bufs[w >> 1], S4, S3, S2, a1a, l, a, b);
    __syncthreads();

    // common per-thread indices for bulk S4 work (l-major float4 units)
    const int ce = t >> 4;            // 0..63
    const int cc = ce >> 3, ee = ce & 7;
    const int l0 = (t & 15) * 4;      // quad of lanes, same a
    const int aa = l0 >> 3, b0 = l0 & 7;

    // ---- parallel round 1: (0,1)->0 (2,3)->2 (4,5)->4 (6,7)->6 ----
    {
        float r4[16];
        #pragma unroll
        for (int k = 0; k < 4; ++k) {
            const CBuf& L = bufs[2 * k];
            const CBuf& R = bufs[2 * k + 1];
            const float4 A4 = *(const float4*)&L.T4t[ce * 64 + l0];
            const float4 T4 = *(const float4*)&R.T4t[ce * 64 + l0];
            const float4 A2 = *(const float4*)&L.T2[l0];
            const float T1e = R.T1[ee];
            const float T2ce = R.T2[cc * 8 + ee];
            const float A1a = L.T1[aa];
            const float A4r[4] = {A4.x, A4.y, A4.z, A4.w};
            const float T4r[4] = {T4.x, T4.y, T4.z, T4.w};
            const float A2r[4] = {A2.x, A2.y, A2.z, A2.w};
            #pragma unroll
            for (int j = 0; j < 4; ++j) {
                const float A3s = L.T3b[aa * 68 + (b0 + j) * 8 + cc];
                const float T3s = R.T3b[(b0 + j) * 68 + cc * 8 + ee];
                r4[k * 4 + j] = A4r[j] + A3s * T1e + A2r[j] * T2ce + A1a * T3s + T4r[j];
            }
        }
        float r3[2];
        #pragma unroll
        for (int jj = 0; jj < 2; ++jj) {
            const int f = 2 * t + jj;
            const int p = f >> 9, idx = f & 511;
            const CBuf& L = bufs[2 * p];
            const CBuf& R = bufs[2 * p + 1];
            const int a3 = idx >> 6, b3 = (idx >> 3) & 7, c3 = idx & 7;
            r3[jj] = L.T3b[a3 * 68 + b3 * 8 + c3] + L.T2[a3 * 8 + b3] * R.T1[c3]
                   + L.T1[a3] * R.T2[b3 * 8 + c3] + R.T3b[a3 * 68 + b3 * 8 + c3];
        }
        float r2 = 0.f, r1 = 0.f;
        if (t < 256) {
            const int p = t >> 6, idx = t & 63;
            r2 = bufs[2 * p].T2[idx] + bufs[2 * p].T1[idx >> 3] * bufs[2 * p + 1].T1[idx & 7]
               + bufs[2 * p + 1].T2[idx];
        }
        if (t < 32) r1 = bufs[2 * (t >> 3)].T1[t & 7] + bufs[2 * (t >> 3) + 1].T1[t & 7];
        __syncthreads();
        #pragma unroll
        for (int k = 0; k < 4; ++k)
            *(float4*)&bufs[2 * k].T4t[ce * 64 + l0] =
                make_float4(r4[k * 4], r4[k * 4 + 1], r4[k * 4 + 2], r4[k * 4 + 3]);
        #pragma unroll
        for (int jj = 0; jj < 2; ++jj) {
            const int f = 2 * t + jj;
            const int p = f >> 9, idx = f & 511;
            bufs[2 * p].T3b[(idx >> 6) * 68 + ((idx >> 3) & 7) * 8 + (idx & 7)] = r3[jj];
        }
        if (t < 256) bufs[2 * (t >> 6)].T2[t & 63] = r2;
        if (t < 32)  bufs[2 * (t >> 3)].T1[t & 7] = r1;
        __syncthreads();
    }

    // ---- parallel round 2: (0,2)->0 (4,6)->4 ----
    {
        float r4[8];
        #pragma unroll
        for (int k = 0; k < 2; ++k) {
            const CBuf& L = bufs[4 * k];
            const CBuf& R = bufs[4 * k + 2];
            const float4 A4 = *(const float4*)&L.T4t[ce * 64 + l0];
            const float4 T4 = *(const float4*)&R.T4t[ce * 64 + l0];
            const float4 A2 = *(const float4*)&L.T2[l0];
            const float T1e = R.T1[ee];
            const float T2ce = R.T2[cc * 8 + ee];
            const float A1a = L.T1[aa];
            const float A4r[4] = {A4.x, A4.y, A4.z, A4.w};
            const float T4r[4] = {T4.x, T4.y, T4.z, T4.w};
            const float A2r[4] = {A2.x, A2.y, A2.z, A2.w};
            #pragma unroll
            for (int j = 0; j < 4; ++j) {
                const float A3s = L.T3b[aa * 68 + (b0 + j) * 8 + cc];
                const float T3s = R.T3b[(b0 + j) * 68 + cc * 8 + ee];
                r4[k * 4 + j] = A4r[j] + A3s * T1e + A2r[j] * T2ce + A1a * T3s + T4r[j];
            }
        }
        float r3;
        {
            const int p = t >> 9, idx = t & 511;
            const CBuf& L = bufs[4 * p];
            const CBuf& R = bufs[4 * p + 2];
            const int a3 = idx >> 6, b3 = (idx >> 3) & 7, c3 = idx & 7;
            r3 = L.T3b[a3 * 68 + b3 * 8 + c3] + L.T2[a3 * 8 + b3] * R.T1[c3]
               + L.T1[a3] * R.T2[b3 * 8 + c3] + R.T3b[a3 * 68 + b3 * 8 + c3];
        }
        float r2 = 0.f, r1 = 0.f;
        if (t < 128) {
            const int p = t >> 6, idx = t & 63;
            r2 = bufs[4 * p].T2[idx] + bufs[4 * p].T1[idx >> 3] * bufs[4 * p + 2].T1[idx & 7]
               + bufs[4 * p + 2].T2[idx];
        }
        if (t < 16) r1 = bufs[4 * (t >> 3)].T1[t & 7] + bufs[4 * (t >> 3) + 2].T1[t & 7];
        __syncthreads();
        #pragma unroll
        for (int k = 0; k < 2; ++k)
            *(float4*)&bufs[4 * k].T4t[ce * 64 + l0] =
                make_float4(r4[k * 4], r4[k * 4 + 1], r4[k * 4 + 2], r4[k * 4 + 3]);
        {
            const int p = t >> 9, idx = t & 511;
            bufs[4 * p].T3b[(idx >> 6) * 68 + ((idx >> 3) & 7) * 8 + (idx & 7)] = r3;
        }
        if (t < 128) bufs[4 * (t >> 6)].T2[t & 63] = r2;
        if (t < 16)  bufs[4 * (t >> 3)].T1[t & 7] = r1;
        __syncthreads();
    }

    // ---- parallel round 3: (0,4) -> global, coalesced float4 along last index ----
    {
        const CBuf& L = bufs[0];
        const CBuf& R = bufs[4];
        float* o = out + n * SIGLEN;
        // S4: thread t -> abc = t>>1, e-half = t&1
        {
            const int abc = t >> 1, e0 = (t & 1) * 4;
            const int a4 = abc >> 6, b4 = (abc >> 3) & 7, c4 = abc & 7;
            const int ll = a4 * 8 + b4;
            const float4 T1v = *(const float4*)&R.T1[e0];
            const float4 T2v = *(const float4*)&R.T2[c4 * 8 + e0];
            const float4 T3v = *(const float4*)&R.T3b[b4 * 68 + c4 * 8 + e0];
            const float A3s = L.T3b[a4 * 68 + b4 * 8 + c4];
            const float A2s = L.T2[ll];
            const float A1s = L.T1[a4];
            const float T1r[4] = {T1v.x, T1v.y, T1v.z, T1v.w};
            const float T2r[4] = {T2v.x, T2v.y, T2v.z, T2v.w};
            const float T3r[4] = {T3v.x, T3v.y, T3v.z, T3v.w};
            float rv[4];
            #pragma unroll
            for (int j = 0; j < 4; ++j)
                rv[j] = L.T4t[(c4 * 8 + e0 + j) * 64 + ll]
                      + A3s * T1r[j] + A2s * T2r[j] + A1s * T3r[j]
                      + R.T4t[(c4 * 8 + e0 + j) * 64 + ll];
            *(float4*)&o[584 + abc * 8 + e0] = make_float4(rv[0], rv[1], rv[2], rv[3]);
        }
        // S3: threads 0..127 -> ab = t>>1, c-half = t&1
        if (t < 128) {
            const int ab = t >> 1, c0 = (t & 1) * 4;
            const int a3 = ab >> 3, b3 = ab & 7;
            float rv[4];
            #pragma unroll
            for (int j = 0; j < 4; ++j)
                rv[j] = L.T3b[a3 * 68 + b3 * 8 + c0 + j]
                      + L.T2[ab] * R.T1[c0 + j]
                      + L.T1[a3] * R.T2[b3 * 8 + c0 + j]
                      + R.T3b[a3 * 68 + b3 * 8 + c0 + j];
            *(float4*)&o[72 + ab * 8 + c0] = make_float4(rv[0], rv[1], rv[2], rv[3]);
        }
        // S2: threads 0..15
        if (t < 16) {
            const int a2 = t >> 1, b02 = (t & 1) * 4;
            float rv[4];
            #pragma unroll
            for (int j = 0; j < 4; ++j)
                rv[j] = L.T2[a2 * 8 + b02 + j] + L.T1[a2] * R.T1[b02 + j]
                      + R.T2[a2 * 8 + b02 + j];
            *(float4*)&o[8 + a2 * 8 + b02] = make_float4(rv[0], rv[1], rv[2], rv[3]);
        }
        // S1: threads 0..1
        if (t < 2) {
            float rv[4];
            #pragma unroll
            for (int j = 0; j < 4; ++j)
                rv[j] = L.T1[t * 4 + j] + R.T1[t * 4 + j];
            *(float4*)&o[t * 4] = make_float4(rv[0], rv[1], rv[2], rv[3]);
        }
    }
}

extern "C" void kernel_launch(void* const* d_in, const int* in_sizes, int n_in,
                              void* d_out, int out_size, void* d_ws, size_t ws_size,
                              hipStream_t stream) {
    const float* path = (const float*)d_in[0];
    float* out = (float*)d_out;
    sig_kernel<<<NBATCH, 1024, 0, stream>>>(path, out);
}

// Round 5
// 25.509 us; speedup vs baseline: 1.9237x; 1.9237x over previous
//
#include <hip/hip_runtime.h>

#define NBATCH 32
#define LPATH 256
#define NSEG 255
#define SIGLEN 4680       // 8 + 64 + 512 + 4096
#define INV6 (1.0f/6.0f)
#define INV24 (1.0f/24.0f)

// Per-signature LDS buffer, exchange-friendly layouts:
//  T4t : level-4 transposed [ (c*8+e)*64 + (a*8+b) ]
//  T3b : level-3 padded      [ x*68 + y*8 + z ]
//  T2  : [ a*8+b ]    T1 : [ a ]
struct __align__(16) CBuf {
    float T4t[64 * 64];   // 16384 B
    float T3b[8 * 68];    //  2176 B
    float T2[64];         //   256 B
    float T1[8];          //    32 B
};                        // 18848 B; x8 = 150784 B

__device__ __forceinline__ void publish_sig(CBuf& B, const float S4[64],
                                            const float S3[8], float S2, float a1a,
                                            int l, int a, int b) {
    #pragma unroll
    for (int c = 0; c < 8; ++c)
        #pragma unroll
        for (int e = 0; e < 8; ++e)
            B.T4t[(c * 8 + e) * 64 + l] = S4[c * 8 + e];
    #pragma unroll
    for (int c = 0; c < 8; ++c)
        B.T3b[a * 68 + b * 8 + c] = S3[c];
    B.T2[l] = S2;
    if (b == 0) B.T1[a] = a1a;
}

__device__ __forceinline__ void absorb_sig(const CBuf& B, float S4[64], float S3[8],
                                           float& S2, float& a1a, int l, int a, int b) {
    const float4 t1lo = *(const float4*)&B.T1[0];
    const float4 t1hi = *(const float4*)&B.T1[4];
    const float t1r[8] = {t1lo.x, t1lo.y, t1lo.z, t1lo.w,
                          t1hi.x, t1hi.y, t1hi.z, t1hi.w};
    const float t1a = B.T1[a];
    const float t1b = B.T1[b];
    #pragma unroll
    for (int c = 0; c < 8; ++c) {
        const float4 t2lo = *(const float4*)&B.T2[c * 8];
        const float4 t2hi = *(const float4*)&B.T2[c * 8 + 4];
        const float t2r[8] = {t2lo.x, t2lo.y, t2lo.z, t2lo.w,
                              t2hi.x, t2hi.y, t2hi.z, t2hi.w};
        const float4 t3lo = *(const float4*)&B.T3b[b * 68 + c * 8];
        const float4 t3hi = *(const float4*)&B.T3b[b * 68 + c * 8 + 4];
        const float t3r[8] = {t3lo.x, t3lo.y, t3lo.z, t3lo.w,
                              t3hi.x, t3hi.y, t3hi.z, t3hi.w};
        #pragma unroll
        for (int e = 0; e < 8; ++e)
            S4[c * 8 + e] += S3[c] * t1r[e] + S2 * t2r[e]
                           + a1a * t3r[e] + B.T4t[(c * 8 + e) * 64 + l];
    }
    #pragma unroll
    for (int c = 0; c < 8; ++c)
        S3[c] += S2 * t1r[c] + a1a * B.T2[b * 8 + c] + B.T3b[a * 68 + b * 8 + c];
    S2 += a1a * t1b + B.T2[l];
    a1a += t1a;
}

// One block per batch; 1024 threads = 16 waves. Wave w scans segments
// [16w,16w+16) (seg 255 padded to identity) from an LDS increment buffer,
// then: round0 wave-pair combine, survivors publish, rounds 1-3 all-thread.
__global__ __launch_bounds__(1024) void sig_kernel(const float* __restrict__ path,
                                                   float* __restrict__ out) {
    const int n = blockIdx.x;
    const int t = threadIdx.x;
    const int w = t >> 6, l = t & 63, a = l >> 3, b = l & 7;

    __shared__ CBuf bufs[8];
    __shared__ float dbuf[2048];   // 256 segs x 8 (seg 255 = 0 pad)

    const float* prow = path + n * (LPATH * 8);
    #pragma unroll
    for (int i = t; i < 2048; i += 1024)
        dbuf[i] = (i < NSEG * 8) ? (prow[i + 8] - prow[i]) : 0.f;
    __syncthreads();

    float S4[64], S3[8], S2 = 0.f, a1a = 0.f;
    #pragma unroll
    for (int j = 0; j < 64; ++j) S4[j] = 0.f;
    #pragma unroll
    for (int c = 0; c < 8; ++c) S3[c] = 0.f;

    // ---- scan 16 segments from LDS (broadcast reads, conflict-free) ----
    #pragma unroll 4
    for (int ss = 0; ss < 16; ++ss) {
        const int s = (w << 4) + ss;
        const float4 dlo = *(const float4*)&dbuf[s * 8];
        const float4 dhi = *(const float4*)&dbuf[s * 8 + 4];
        const float dr[8] = {dlo.x, dlo.y, dlo.z, dlo.w, dhi.x, dhi.y, dhi.z, dhi.w};
        const float da = dbuf[s * 8 + a];
        const float db = dbuf[s * 8 + b];
        const float dab = da * db;
        const float P = dab * INV24 + a1a * db * INV6 + S2 * 0.5f;
        const float Q = dab * INV6  + a1a * db * 0.5f + S2;
        float K[8];
        #pragma unroll
        for (int c = 0; c < 8; ++c) K[c] = dr[c] * P + S3[c];
        #pragma unroll
        for (int c = 0; c < 8; ++c)
            #pragma unroll
            for (int e = 0; e < 8; ++e)
                S4[c * 8 + e] += dr[e] * K[c];
        #pragma unroll
        for (int c = 0; c < 8; ++c) S3[c] += dr[c] * Q;
        S2 += db * (da * 0.5f + a1a);
        a1a += da;
    }

    // ---- round 0: wave-pair tree (odd waves publish, even absorb) ----
    if (w & 1) publish_sig(bufs[w >> 1], S4, S3, S2, a1a, l, a, b);
    __syncthreads();
    if (!(w & 1)) absorb_sig(bufs[w >> 1], S4, S3, S2, a1a, l, a, b);
    __syncthreads();

    // ---- survivors publish combined sigs into bufs[0..7] ----
    if (!(w & 1)) publish_sig(bufs[w >> 1], S4, S3, S2, a1a, l, a, b);
    __syncthreads();

    // common per-thread indices for bulk S4 work (l-major float4 units)
    const int ce = t >> 4;            // 0..63
    const int cc = ce >> 3, ee = ce & 7;
    const int l0 = (t & 15) * 4;      // quad of lanes, same a
    const int aa = l0 >> 3, b0 = l0 & 7;

    // ---- parallel round 1: (0,1)->0 (2,3)->2 (4,5)->4 (6,7)->6 ----
    {
        float r4[16];
        #pragma unroll
        for (int k = 0; k < 4; ++k) {
            const CBuf& L = bufs[2 * k];
            const CBuf& R = bufs[2 * k + 1];
            const float4 A4 = *(const float4*)&L.T4t[ce * 64 + l0];
            const float4 T4 = *(const float4*)&R.T4t[ce * 64 + l0];
            const float4 A2 = *(const float4*)&L.T2[l0];
            const float T1e = R.T1[ee];
            const float T2ce = R.T2[cc * 8 + ee];
            const float A1a = L.T1[aa];
            const float A4r[4] = {A4.x, A4.y, A4.z, A4.w};
            const float T4r[4] = {T4.x, T4.y, T4.z, T4.w};
            const float A2r[4] = {A2.x, A2.y, A2.z, A2.w};
            #pragma unroll
            for (int j = 0; j < 4; ++j) {
                const float A3s = L.T3b[aa * 68 + (b0 + j) * 8 + cc];
                const float T3s = R.T3b[(b0 + j) * 68 + cc * 8 + ee];
                r4[k * 4 + j] = A4r[j] + A3s * T1e + A2r[j] * T2ce + A1a * T3s + T4r[j];
            }
        }
        float r3[2];
        #pragma unroll
        for (int jj = 0; jj < 2; ++jj) {
            const int f = 2 * t + jj;
            const int p = f >> 9, idx = f & 511;
            const CBuf& L = bufs[2 * p];
            const CBuf& R = bufs[2 * p + 1];
            const int a3 = idx >> 6, b3 = (idx >> 3) & 7, c3 = idx & 7;
            r3[jj] = L.T3b[a3 * 68 + b3 * 8 + c3] + L.T2[a3 * 8 + b3] * R.T1[c3]
                   + L.T1[a3] * R.T2[b3 * 8 + c3] + R.T3b[a3 * 68 + b3 * 8 + c3];
        }
        float r2 = 0.f, r1 = 0.f;
        if (t < 256) {
            const int p = t >> 6, idx = t & 63;
            r2 = bufs[2 * p].T2[idx] + bufs[2 * p].T1[idx >> 3] * bufs[2 * p + 1].T1[idx & 7]
               + bufs[2 * p + 1].T2[idx];
        }
        if (t < 32) r1 = bufs[2 * (t >> 3)].T1[t & 7] + bufs[2 * (t >> 3) + 1].T1[t & 7];
        __syncthreads();
        #pragma unroll
        for (int k = 0; k < 4; ++k)
            *(float4*)&bufs[2 * k].T4t[ce * 64 + l0] =
                make_float4(r4[k * 4], r4[k * 4 + 1], r4[k * 4 + 2], r4[k * 4 + 3]);
        #pragma unroll
        for (int jj = 0; jj < 2; ++jj) {
            const int f = 2 * t + jj;
            const int p = f >> 9, idx = f & 511;
            bufs[2 * p].T3b[(idx >> 6) * 68 + ((idx >> 3) & 7) * 8 + (idx & 7)] = r3[jj];
        }
        if (t < 256) bufs[2 * (t >> 6)].T2[t & 63] = r2;
        if (t < 32)  bufs[2 * (t >> 3)].T1[t & 7] = r1;
        __syncthreads();
    }

    // ---- parallel round 2: (0,2)->0 (4,6)->4 ----
    {
        float r4[8];
        #pragma unroll
        for (int k = 0; k < 2; ++k) {
            const CBuf& L = bufs[4 * k];
            const CBuf& R = bufs[4 * k + 2];
            const float4 A4 = *(const float4*)&L.T4t[ce * 64 + l0];
            const float4 T4 = *(const float4*)&R.T4t[ce * 64 + l0];
            const float4 A2 = *(const float4*)&L.T2[l0];
            const float T1e = R.T1[ee];
            const float T2ce = R.T2[cc * 8 + ee];
            const float A1a = L.T1[aa];
            const float A4r[4] = {A4.x, A4.y, A4.z, A4.w};
            const float T4r[4] = {T4.x, T4.y, T4.z, T4.w};
            const float A2r[4] = {A2.x, A2.y, A2.z, A2.w};
            #pragma unroll
            for (int j = 0; j < 4; ++j) {
                const float A3s = L.T3b[aa * 68 + (b0 + j) * 8 + cc];
                const float T3s = R.T3b[(b0 + j) * 68 + cc * 8 + ee];
                r4[k * 4 + j] = A4r[j] + A3s * T1e + A2r[j] * T2ce + A1a * T3s + T4r[j];
            }
        }
        float r3;
        {
            const int p = t >> 9, idx = t & 511;
            const CBuf& L = bufs[4 * p];
            const CBuf& R = bufs[4 * p + 2];
            const int a3 = idx >> 6, b3 = (idx >> 3) & 7, c3 = idx & 7;
            r3 = L.T3b[a3 * 68 + b3 * 8 + c3] + L.T2[a3 * 8 + b3] * R.T1[c3]
               + L.T1[a3] * R.T2[b3 * 8 + c3] + R.T3b[a3 * 68 + b3 * 8 + c3];
        }
        float r2 = 0.f, r1 = 0.f;
        if (t < 128) {
            const int p = t >> 6, idx = t & 63;
            r2 = bufs[4 * p].T2[idx] + bufs[4 * p].T1[idx >> 3] * bufs[4 * p + 2].T1[idx & 7]
               + bufs[4 * p + 2].T2[idx];
        }
        if (t < 16) r1 = bufs[4 * (t >> 3)].T1[t & 7] + bufs[4 * (t >> 3) + 2].T1[t & 7];
        __syncthreads();
        #pragma unroll
        for (int k = 0; k < 2; ++k)
            *(float4*)&bufs[4 * k].T4t[ce * 64 + l0] =
                make_float4(r4[k * 4], r4[k * 4 + 1], r4[k * 4 + 2], r4[k * 4 + 3]);
        {
            const int p = t >> 9, idx = t & 511;
            bufs[4 * p].T3b[(idx >> 6) * 68 + ((idx >> 3) & 7) * 8 + (idx & 7)] = r3;
        }
        if (t < 128) bufs[4 * (t >> 6)].T2[t & 63] = r2;
        if (t < 16)  bufs[4 * (t >> 3)].T1[t & 7] = r1;
        __syncthreads();
    }

    // ---- parallel round 3: (0,4) -> global, coalesced float4 along last index ----
    {
        const CBuf& L = bufs[0];
        const CBuf& R = bufs[4];
        float* o = out + n * SIGLEN;
        {
            const int abc = t >> 1, e0 = (t & 1) * 4;
            const int a4 = abc >> 6, b4 = (abc >> 3) & 7, c4 = abc & 7;
            const int ll = a4 * 8 + b4;
            const float4 T1v = *(const float4*)&R.T1[e0];
            const float4 T2v = *(const float4*)&R.T2[c4 * 8 + e0];
            const float4 T3v = *(const float4*)&R.T3b[b4 * 68 + c4 * 8 + e0];
            const float A3s = L.T3b[a4 * 68 + b4 * 8 + c4];
            const float A2s = L.T2[ll];
            const float A1s = L.T1[a4];
            const float T1r[4] = {T1v.x, T1v.y, T1v.z, T1v.w};
            const float T2r[4] = {T2v.x, T2v.y, T2v.z, T2v.w};
            const float T3r[4] = {T3v.x, T3v.y, T3v.z, T3v.w};
            float rv[4];
            #pragma unroll
            for (int j = 0; j < 4; ++j)
                rv[j] = L.T4t[(c4 * 8 + e0 + j) * 64 + ll]
                      + A3s * T1r[j] + A2s * T2r[j] + A1s * T3r[j]
                      + R.T4t[(c4 * 8 + e0 + j) * 64 + ll];
            *(float4*)&o[584 + abc * 8 + e0] = make_float4(rv[0], rv[1], rv[2], rv[3]);
        }
        if (t < 128) {
            const int ab = t >> 1, c0 = (t & 1) * 4;
            const int a3 = ab >> 3, b3 = ab & 7;
            float rv[4];
            #pragma unroll
            for (int j = 0; j < 4; ++j)
                rv[j] = L.T3b[a3 * 68 + b3 * 8 + c0 + j]
                      + L.T2[ab] * R.T1[c0 + j]
                      + L.T1[a3] * R.T2[b3 * 8 + c0 + j]
                      + R.T3b[a3 * 68 + b3 * 8 + c0 + j];
            *(float4*)&o[72 + ab * 8 + c0] = make_float4(rv[0], rv[1], rv[2], rv[3]);
        }
        if (t < 16) {
            const int a2 = t >> 1, b02 = (t & 1) * 4;
            float rv[4];
            #pragma unroll
            for (int j = 0; j < 4; ++j)
                rv[j] = L.T2[a2 * 8 + b02 + j] + L.T1[a2] * R.T1[b02 + j]
                      + R.T2[a2 * 8 + b02 + j];
            *(float4*)&o[8 + a2 * 8 + b02] = make_float4(rv[0], rv[1], rv[2], rv[3]);
        }
        if (t < 2) {
            float rv[4];
            #pragma unroll
            for (int j = 0; j < 4; ++j)
                rv[j] = L.T1[t * 4 + j] + R.T1[t * 4 + j];
            *(float4*)&o[t * 4] = make_float4(rv[0], rv[1], rv[2], rv[3]);
        }
    }
}

extern "C" void kernel_launch(void* const* d_in, const int* in_sizes, int n_in,
                              void* d_out, int out_size, void* d_ws, size_t ws_size,
                              hipStream_t stream) {
    const float* path = (const float*)d_in[0];
    float* out = (float*)d_out;
    sig_kernel<<<NBATCH, 1024, 0, stream>>>(path, out);
}

// Round 7
// 18.942 us; speedup vs baseline: 2.5906x; 1.3467x over previous
//
#include <hip/hip_runtime.h>

#define NBATCH 32
#define LPATH 256
#define NSEG 255
#define SIGLEN 4680       // 8 + 64 + 512 + 4096
#define INV6 (1.0f/6.0f)
#define INV24 (1.0f/24.0f)

typedef float v2f __attribute__((ext_vector_type(2)));

// Per-signature LDS buffer, exchange-friendly layouts:
//  T4t2 : level-4, e-pairs contiguous per lane: [ (c*4+eh)*128 + 2*l + p ]
//         (lane l=(a<<3)|b owns elements (a,b,c,2eh+p)) -> b64 r/w, contiguous
//  T3b  : level-3 padded [ x*68 + y*8 + z ]
//  T2   : [ a*8+b ]    T1 : [ a ]
struct __align__(16) CBuf {
    float T4t2[64 * 64];  // 16384 B
    float T3b[8 * 68];    //  2176 B
    float T2[64];         //   256 B
    float T1[8];          //    32 B
};                        // 18848 B; x4 = 75392 B

__device__ __forceinline__ void publish_sig(CBuf& B, const v2f S4v[32],
                                            const float S3[8], float S2, float a1a,
                                            int l, int a, int b) {
    #pragma unroll
    for (int ch = 0; ch < 32; ++ch)
        *(v2f*)&B.T4t2[ch * 128 + 2 * l] = S4v[ch];
    #pragma unroll
    for (int c = 0; c < 8; ++c)
        B.T3b[a * 68 + b * 8 + c] = S3[c];
    B.T2[l] = S2;
    if (b == 0) B.T1[a] = a1a;
}

__device__ __forceinline__ void absorb_sig(const CBuf& B, v2f S4v[32], float S3[8],
                                           float& S2, float& a1a, int l, int a, int b) {
    v2f t1v[4];
    #pragma unroll
    for (int h = 0; h < 4; ++h) t1v[h] = *(const v2f*)&B.T1[2 * h];
    const float t1a = B.T1[a];
    const float t1b = B.T1[b];
    const v2f S2v = S2, a1v = a1a;
    // R4[abce] = A4 + A3[abc] T1[e] + A2[ab] T2[ce] + A1[a] T3[bce] + T4
    #pragma unroll
    for (int c = 0; c < 8; ++c) {
        const v2f S3cv = S3[c];
        #pragma unroll
        for (int h = 0; h < 4; ++h) {
            const v2f t2v = *(const v2f*)&B.T2[c * 8 + 2 * h];
            const v2f t3v = *(const v2f*)&B.T3b[b * 68 + c * 8 + 2 * h];
            const v2f t4v = *(const v2f*)&B.T4t2[(c * 4 + h) * 128 + 2 * l];
            v2f acc = S4v[c * 4 + h] + t4v;
            acc = __builtin_elementwise_fma(S3cv, t1v[h], acc);
            acc = __builtin_elementwise_fma(S2v, t2v, acc);
            acc = __builtin_elementwise_fma(a1v, t3v, acc);
            S4v[c * 4 + h] = acc;
        }
    }
    // R3[abc] = A3 + A2[ab] T1[c] + A1[a] T2[bc] + T3[abc]
    #pragma unroll
    for (int c = 0; c < 8; ++c)
        S3[c] += S2 * B.T1[c] + a1a * B.T2[b * 8 + c] + B.T3b[a * 68 + b * 8 + c];
    S2 += a1a * t1b + B.T2[l];
    a1a += t1a;
}

// One block per batch; 512 threads = 8 waves. Wave w scans segments
// [32w,32w+32) (seg 255 zero-padded == identity) from LDS increments,
// then 3-round wave-pair tree; wave 0 writes the signature.
__global__ __launch_bounds__(512) void sig_kernel(const float* __restrict__ path,
                                                  float* __restrict__ out) {
    const int n = blockIdx.x;
    const int t = threadIdx.x;
    const int w = t >> 6, l = t & 63, a = l >> 3, b = l & 7;

    __shared__ CBuf bufs[4];
    __shared__ float dbuf[2048];   // 256 segs x 8 (seg 255 = 0 pad)

    const float* prow = path + n * (LPATH * 8);
    {
        const int i4 = t * 4;
        if (i4 < NSEG * 8) {       // i4 <= 2036: full diff quad (reads up to 2047)
            const float4 x0 = *(const float4*)&prow[i4];
            const float4 x1 = *(const float4*)&prow[i4 + 8];
            *(float4*)&dbuf[i4] = make_float4(x1.x - x0.x, x1.y - x0.y,
                                              x1.z - x0.z, x1.w - x0.w);
        } else {                   // i4 = 2040, 2044: pad segment 255
            *(float4*)&dbuf[i4] = make_float4(0.f, 0.f, 0.f, 0.f);
        }
    }
    __syncthreads();

    v2f S4v[32];
    float S3[8];
    #pragma unroll
    for (int j = 0; j < 32; ++j) S4v[j] = (v2f)0.f;
    #pragma unroll
    for (int c = 0; c < 8; ++c) S3[c] = 0.f;
    float S2 = 0.f, a1a = 0.f;

    // ---- scan 32 segments from LDS (broadcast reads, conflict-free) ----
    #pragma unroll 2
    for (int ss = 0; ss < 32; ++ss) {
        const int s = (w << 5) + ss;
        const float4 dlo = *(const float4*)&dbuf[s * 8];
        const float4 dhi = *(const float4*)&dbuf[s * 8 + 4];
        const v2f dp[4] = {{dlo.x, dlo.y}, {dlo.z, dlo.w},
                           {dhi.x, dhi.y}, {dhi.z, dhi.w}};
        const float da = dbuf[s * 8 + a];
        const float db = dbuf[s * 8 + b];
        const float dab = da * db;
        const float P = dab * INV24 + a1a * db * INV6 + S2 * 0.5f;
        const float Q = dab * INV6  + a1a * db * 0.5f + S2;
        const v2f Pv = P, Qv = Q;
        // K[c-pair] = d[c-pair]*P + oldS3[c-pair]; S3 += d*Q
        v2f Kv[4];
        #pragma unroll
        for (int h = 0; h < 4; ++h) {
            v2f S3h = {S3[2 * h], S3[2 * h + 1]};
            Kv[h] = __builtin_elementwise_fma(dp[h], Pv, S3h);
            S3h = __builtin_elementwise_fma(dp[h], Qv, S3h);
            S3[2 * h] = S3h.x; S3[2 * h + 1] = S3h.y;
        }
        // S4[c][e-pair] += d[e-pair] * K[c]
        #pragma unroll
        for (int c = 0; c < 8; ++c) {
            const float Kc = (c & 1) ? Kv[c >> 1].y : Kv[c >> 1].x;
            const v2f Kcv = Kc;
            #pragma unroll
            for (int h = 0; h < 4; ++h)
                S4v[c * 4 + h] = __builtin_elementwise_fma(dp[h], Kcv, S4v[c * 4 + h]);
        }
        S2 += db * (da * 0.5f + a1a);
        a1a += da;
    }

    // ---- 3-round wave-pair tree; wave 0 ends with the full signature ----
    #pragma unroll
    for (int r = 0; r < 3; ++r) {
        const int stride = 1 << r;
        const int m = (stride << 1) - 1;
        if ((w & m) == stride)
            publish_sig(bufs[w >> (r + 1)], S4v, S3, S2, a1a, l, a, b);
        __syncthreads();
        if ((w & m) == 0)
            absorb_sig(bufs[w >> (r + 1)], S4v, S3, S2, a1a, l, a, b);
        __syncthreads();
    }

    // ---- wave 0 writes [S1|S2|S3|S4] ----
    if (w == 0) {
        float* o = out + n * SIGLEN;
        if (b == 0) o[a] = a1a;
        o[8 + l] = S2;
        *(float4*)&o[72 + l * 8]     = make_float4(S3[0], S3[1], S3[2], S3[3]);
        *(float4*)&o[72 + l * 8 + 4] = make_float4(S3[4], S3[5], S3[6], S3[7]);
        #pragma unroll
        for (int ch = 0; ch < 32; ++ch)
            *(v2f*)&o[584 + l * 64 + 2 * ch] = S4v[ch];   // c*8+2h+p ordering
    }
}

extern "C" void kernel_launch(void* const* d_in, const int* in_sizes, int n_in,
                              void* d_out, int out_size, void* d_ws, size_t ws_size,
                              hipStream_t stream) {
    const float* path = (const float*)d_in[0];
    float* out = (float*)d_out;
    sig_kernel<<<NBATCH, 512, 0, stream>>>(path, out);
}